// Round 8
// baseline (1958.465 us; speedup 1.0000x reference)
//
#include <hip/hip_runtime.h>
#include <hip/hip_bf16.h>
#include <math.h>

#define Bsz 1024
#define Hd  256
#define MAXTILE 40               // max row-tiles per cell (worst case: 9 buckets -> exactly 40)
#define PERM_PER_CELL (MAXTILE*32)
#define WTSTRIDE (768*512)       // one combo matrix, TRANSPOSED: [col(768)][k(512)] bf16
#define GHALF (Bsz*768)          // one split-k partial buffer (f32)
#define NPART 4                  // split-k partials (2 per neighbor half)

typedef short bf16x8 __attribute__((ext_vector_type(8)));   // 8 bf16 in 4 VGPRs
typedef float f32x4  __attribute__((ext_vector_type(4)));   // MFMA accumulator

// ---------- build 16 combined weight matrices, transposed + bf16-split ------
// Wt[c][col][k] = (a<3?W1|W2[a][k][col]:0) + (b<3?W1|W2[3+b][k][col]:0) | Wm[k][col-512]
// stored as bf16 high (Wht) + bf16 residual (Wlt); idx = (c*768+col)*512 + k
__global__ __launch_bounds__(256)
void build_wc(const float* __restrict__ W1, const float* __restrict__ W2,
              const float* __restrict__ Wm,
              __hip_bfloat16* __restrict__ Wht, __hip_bfloat16* __restrict__ Wlt)
{
    size_t idx = (size_t)blockIdx.x * 256 + threadIdx.x;   // < 16*768*512
    int k = (int)(idx & 511);
    size_t rem = idx >> 9;
    int col = (int)(rem % 768);
    int c = (int)(rem / 768);
    int a = c >> 2, b = c & 3;
    float v;
    if (col < 256) {
        v = ((a < 3) ? W1[(size_t)a * 512 * 256 + k * 256 + col] : 0.f)
          + ((b < 3) ? W1[(size_t)(3 + b) * 512 * 256 + k * 256 + col] : 0.f);
    } else if (col < 512) {
        int cc = col - 256;
        v = ((a < 3) ? W2[(size_t)a * 512 * 256 + k * 256 + cc] : 0.f)
          + ((b < 3) ? W2[(size_t)(3 + b) * 512 * 256 + k * 256 + cc] : 0.f);
    } else {
        v = Wm[(size_t)k * 256 + (col - 512)];
    }
    __hip_bfloat16 vh = __float2bfloat16(v);
    __hip_bfloat16 vl = __float2bfloat16(v - __bfloat162float(vh));
    Wht[idx] = vh;
    Wlt[idx] = vl;
}

// ---------- bucketize: per cell, sort sample indices by combo ---------------
__global__ __launch_bounds__(256)
void bucketize(const int* __restrict__ samples, int* __restrict__ perm,
               int* __restrict__ tiletab)
{
    const int cell = blockIdx.x;         // 0..63 in snake order
    const int t = threadIdx.x;
    const int ny = cell >> 3, ixs = cell & 7;
    const int nx  = (ny & 1) ? (7 - ixs) : ixs;
    const int dx  = (ny & 1) ? 1 : -1;
    const int nxn = nx + dx;
    const bool hasX = (nxn >= 0) && (nxn < 8);
    const bool hasY = (ny > 0);
    const int sx_off = nxn * 8 + ny;
    const int sy_off = nx * 8 + ny - 1;

    __shared__ int hist[16], cursor[16];
    int* pcell = perm + (size_t)cell * PERM_PER_CELL;
    for (int i = t; i < PERM_PER_CELL; i += 256) pcell[i] = -1;
    if (t < 16) hist[t] = 0;
    __syncthreads();

    int myc[4];
#pragma unroll
    for (int q = 0; q < 4; q++) {
        int l = t * 4 + q;
        int a = hasX ? samples[l * 64 + sx_off] : 3;
        int b = hasY ? samples[l * 64 + sy_off] : 3;
        myc[q] = a * 4 + b;
        atomicAdd(&hist[myc[q]], 1);
    }
    __syncthreads();

    if (t == 0) {
        int tile = 0, row = 0;
        for (int c = 0; c < 16; c++) {
            cursor[c] = row;
            int nt = (hist[c] + 31) >> 5;
            for (int k = 0; k < nt; k++) tiletab[cell * MAXTILE + tile + k] = c;
            tile += nt;
            row  += nt * 32;
        }
        for (; tile < MAXTILE; tile++) tiletab[cell * MAXTILE + tile] = -1;
    }
    __syncthreads();

#pragma unroll
    for (int q = 0; q < 4; q++) {
        int l = t * 4 + q;
        int pos = atomicAdd(&cursor[myc[q]], 1);
        pcell[pos] = l;
    }
}

// ---------------- per-cell bucketed split-k MFMA GEMM -----------------------
// 3-term bf16 split: acc += Ah*Bh + Ah*Bl + Al*Bh  (error ~2^-18 relative)
// grid (12 col-tiles of 64, MAXTILE row-tiles of 32, 4 k-chunks of 128), 256 thr
// wave w computes 32 rows x 16 cols (2 MFMA row-tiles); B staged in LDS swizzled.
__global__ __launch_bounds__(256)
void gemm_mfma(const __hip_bfloat16* __restrict__ hxh, const __hip_bfloat16* __restrict__ hxl,
               const __hip_bfloat16* __restrict__ hyh, const __hip_bfloat16* __restrict__ hyl,
               const __hip_bfloat16* __restrict__ Wht, const __hip_bfloat16* __restrict__ Wlt,
               const int* __restrict__ perm, const int* __restrict__ tiletab,
               float* __restrict__ Gp, int cell, int kbeg, int kend)
{
    const int combo = tiletab[cell * MAXTILE + blockIdx.y];
    if (combo < 0) return;                     // block-uniform exit (before any sync)
    const int chunk = blockIdx.z;              // 0..3
    const int kbase = chunk << 7;              // 0,128,256,384
    const int lo = (kbeg > kbase) ? kbeg : kbase;
    const int hi = (kend < kbase + 128) ? kend : (kbase + 128);
    const int k0 = blockIdx.x * 64;            // col tile base
    const int* pr = perm + (size_t)cell * PERM_PER_CELL + blockIdx.y * 32;
    float* Gout = Gp + (size_t)chunk * GHALF;

    const int t  = threadIdx.x;
    const int w  = t >> 6;                     // wave 0..3
    const int l  = t & 63;                     // lane
    const int lr = l & 15;                     // row/col within MFMA tile
    const int lg = l >> 4;                     // k-group 0..3

    __shared__ __align__(16) short Bh[64 * 128];   // 16 KB, [col][k] swizzled
    __shared__ __align__(16) short Bl[64 * 128];   // 16 KB

    f32x4 acc0 = {0.f, 0.f, 0.f, 0.f};        // row-tile 0 (rows 0..15)
    f32x4 acc1 = {0.f, 0.f, 0.f, 0.f};        // row-tile 1 (rows 16..31)

    if (lo < hi) {                             // full 128-chunk when non-empty
        // ---- stage B tiles (h and l), XOR-swizzled 16B quads ----
        const __hip_bfloat16* baseH = Wht + (size_t)combo * WTSTRIDE + kbase;
        const __hip_bfloat16* baseL = Wlt + (size_t)combo * WTSTRIDE + kbase;
        for (int i = t; i < 1024; i += 256) {
            int c  = i >> 4;                   // local col 0..63
            int kq = i & 15;                   // 16B quad within 128 k
            int q  = c * 16 + (kq ^ (c & 7));  // swizzled quad index
            ((uint4*)Bh)[q] = *(const uint4*)(baseH + (size_t)(k0 + c) * 512 + kq * 8);
            ((uint4*)Bl)[q] = *(const uint4*)(baseL + (size_t)(k0 + c) * 512 + kq * 8);
        }
        __syncthreads();

        const __hip_bfloat16* Hh = (chunk < 2) ? hxh : hyh;
        const __hip_bfloat16* Hl = (chunk < 2) ? hxl : hyl;
        const int hbase = kbase - ((chunk < 2) ? 0 : 256);   // 0 or 128
        const int r0 = pr[lr];                 // A row for row-tile 0 (this lane)
        const int r1 = pr[16 + lr];            // row-tile 1
        const int cB = w * 16 + lr;            // B col (local) for this lane

#pragma unroll
        for (int ks = 0; ks < 4; ks++) {       // 4 k-steps of 32
            const int koff = hbase + ks * 32 + lg * 8;
            bf16x8 a0h = (r0 >= 0) ? *(const bf16x8*)(Hh + (size_t)r0 * Hd + koff) : (bf16x8)0;
            bf16x8 a0l = (r0 >= 0) ? *(const bf16x8*)(Hl + (size_t)r0 * Hd + koff) : (bf16x8)0;
            bf16x8 a1h = (r1 >= 0) ? *(const bf16x8*)(Hh + (size_t)r1 * Hd + koff) : (bf16x8)0;
            bf16x8 a1l = (r1 >= 0) ? *(const bf16x8*)(Hl + (size_t)r1 * Hd + koff) : (bf16x8)0;

            const int kq = ks * 4 + lg;        // quad index within chunk
            const int q  = cB * 16 + (kq ^ (cB & 7));
            bf16x8 bh = ((const bf16x8*)Bh)[q];
            bf16x8 bl = ((const bf16x8*)Bl)[q];

            acc0 = __builtin_amdgcn_mfma_f32_16x16x32_bf16(a0h, bh, acc0, 0, 0, 0);
            acc0 = __builtin_amdgcn_mfma_f32_16x16x32_bf16(a0h, bl, acc0, 0, 0, 0);
            acc0 = __builtin_amdgcn_mfma_f32_16x16x32_bf16(a0l, bh, acc0, 0, 0, 0);
            acc1 = __builtin_amdgcn_mfma_f32_16x16x32_bf16(a1h, bh, acc1, 0, 0, 0);
            acc1 = __builtin_amdgcn_mfma_f32_16x16x32_bf16(a1h, bl, acc1, 0, 0, 0);
            acc1 = __builtin_amdgcn_mfma_f32_16x16x32_bf16(a1l, bh, acc1, 0, 0, 0);
        }
    }

    // ---- C write: D col = lane&15, row = 4*(lane>>4)+reg  (always: zeros ok) ----
    const int colA = k0 + w * 16 + lr;
#pragma unroll
    for (int reg = 0; reg < 4; reg++) {
        const int rl = 4 * lg + reg;
        int ra = pr[rl];
        if (ra >= 0) Gout[(size_t)ra * 768 + colA] = acc0[reg];
        int rb = pr[16 + rl];
        if (rb >= 0) Gout[(size_t)rb * 768 + colA] = acc1[reg];
    }
}

// ------- fused per-cell combine (GRU nonlinearity) + log-prob update --------
// Gp row layout per chunk: [0:256)=pre1, [256:512)=pre2, [512:768)=merge
// Writes h as bf16 split pair (hh,hl) for the next cells' MFMA A-operand.
// kcell==0 bootstraps accumulators; kcell==63 writes d_out.
__global__ __launch_bounds__(256)
void combine_logprob(const float* __restrict__ Gp, const int* __restrict__ samples,
                     const float* __restrict__ b1, const float* __restrict__ b2,
                     const float* __restrict__ Wl1, const float* __restrict__ bl1,
                     const float* __restrict__ Wl2, const float* __restrict__ bl2,
                     __hip_bfloat16* __restrict__ houth, __hip_bfloat16* __restrict__ houtl,
                     float* __restrict__ acc, float* __restrict__ out,
                     int s_off, int kcell)
{
    const int l = blockIdx.x;
    const int k = threadIdx.x;
    const float* g0 = Gp + (size_t)l * 768;

    float pre1 = b1[k], pre2 = b2[k], mg = 0.f;
#pragma unroll
    for (int z = 0; z < NPART; z++) {
        const float* g = g0 + (size_t)z * GHALF;
        pre1 += g[k];
        pre2 += g[256 + k];
        mg   += g[512 + k];
    }
    float ht = tanhf(pre1);
    float u  = 1.0f / (1.0f + expf(-pre2));
    float h  = u * ht + (1.0f - u) * mg;
    __hip_bfloat16 hh = __float2bfloat16(h);
    __hip_bfloat16 hl = __float2bfloat16(h - __bfloat162float(hh));
    houth[(size_t)l * Hd + k] = hh;
    houtl[(size_t)l * Hd + k] = hl;

    // readout dot products (full f32 h): p1[i]=h.Wl1[:,i], p2[i]=h.Wl2[:,i]
    float v[6];
    v[0] = h * Wl1[k * 3 + 0];
    v[1] = h * Wl1[k * 3 + 1];
    v[2] = h * Wl1[k * 3 + 2];
    v[3] = h * Wl2[k * 3 + 0];
    v[4] = h * Wl2[k * 3 + 1];
    v[5] = h * Wl2[k * 3 + 2];
#pragma unroll
    for (int m = 1; m < 64; m <<= 1)
#pragma unroll
        for (int i = 0; i < 6; i++) v[i] += __shfl_xor(v[i], m);

    __shared__ float red[4][6];
    if ((k & 63) == 0) {
#pragma unroll
        for (int i = 0; i < 6; i++) red[k >> 6][i] = v[i];
    }
    __syncthreads();

    if (k == 0) {
        float p1[3], p2[3];
#pragma unroll
        for (int i = 0; i < 3; i++) {
            p1[i] = red[0][i]     + red[1][i]     + red[2][i]     + red[3][i];
            p2[i] = red[0][3 + i] + red[1][3 + i] + red[2][3 + i] + red[3][3 + i];
        }
        float la, lp, nu, nd;
        if (kcell == 0) { la = 0.f; lp = 0.f; nu = 0.f; nd = 0.f; }
        else {
            la = acc[l];           lp = acc[Bsz + l];
            nu = acc[2 * Bsz + l]; nd = acc[3 * Bsz + l];
        }
        float z0 = p1[0] + bl1[0], z1 = p1[1] + bl1[1], z2 = p1[2] + bl1[2];
        float zm = fmaxf(z0, fmaxf(z1, z2));
        float e0 = expf(z0 - zm), e1 = expf(z1 - zm), e2 = expf(z2 - zm);
        float es = e0 + e1 + e2;
        float mh = (16.0f - ((float)kcell - nu - nd) > 0.0f) ? 1.0f : 0.0f;
        float md = (24.0f - nd > 0.0f) ? 1.0f : 0.0f;
        float mu = (24.0f - nu > 0.0f) ? 1.0f : 0.0f;
        float a0 = (e0 / es) * mh, a1 = (e1 / es) * md, a2 = (e2 / es) * mu;
        float asum = fmaxf(a0 + a1 + a2, 1e-30f);
        int sv = samples[l * 64 + s_off];
        float av = ((sv == 0) ? a0 : (sv == 1) ? a1 : a2) / asum;
        float q  = p2[sv] + bl2[sv];
        float ph = 3.14159265358979323846f * (q / (1.0f + fabsf(q)));
        la += logf(fmaxf(av, 1e-12f));
        lp += ph;
        nu += (sv == 2) ? 1.0f : 0.0f;
        nd += (sv == 1) ? 1.0f : 0.0f;
        acc[l] = la; acc[Bsz + l] = lp;
        acc[2 * Bsz + l] = nu; acc[3 * Bsz + l] = nd;
        if (kcell == 63) {
            out[l]       = 0.5f * la;
            out[Bsz + l] = lp;
        }
    }
}

// ---------------------------------------------------------------------------
extern "C" void kernel_launch(void* const* d_in, const int* in_sizes, int n_in,
                              void* d_out, int out_size, void* d_ws, size_t ws_size,
                              hipStream_t stream)
{
    const int*   samples = (const int*)  d_in[0];
    const float* W1  = (const float*)d_in[1];
    const float* b1  = (const float*)d_in[2];
    const float* W2  = (const float*)d_in[3];
    const float* b2  = (const float*)d_in[4];
    const float* Wm  = (const float*)d_in[5];
    const float* Wl1 = (const float*)d_in[6];
    const float* bl1 = (const float*)d_in[7];
    const float* Wl2 = (const float*)d_in[8];
    const float* bl2 = (const float*)d_in[9];

    float* ws = (float*)d_ws;
    float* Gp  = ws;                                        // NPART*B*768 f32
    float* acc = Gp + (size_t)NPART * GHALF;                // 4*B f32
    __hip_bfloat16* Hh  = (__hip_bfloat16*)(acc + 4 * Bsz); // 8*B*H bf16
    __hip_bfloat16* Hl  = Hh + (size_t)8 * Bsz * Hd;
    __hip_bfloat16* Wht = Hl + (size_t)8 * Bsz * Hd;        // 16*768*512 bf16
    __hip_bfloat16* Wlt = Wht + (size_t)16 * WTSTRIDE;
    int* perm    = (int*)(Wlt + (size_t)16 * WTSTRIDE);
    int* tiletab = perm + (size_t)64 * PERM_PER_CELL;
    float* out = (float*)d_out;

    build_wc<<<dim3(16 * 768 * 512 / 256), dim3(256), 0, stream>>>(W1, W2, Wm, Wht, Wlt);
    bucketize<<<dim3(64), dim3(256), 0, stream>>>(samples, perm, tiletab);

    int kcell = 0;
    for (int ny = 0; ny < 8; ny++) {
        const int x0  = (ny % 2 == 0) ? 0 : 7;
        const int dxs = (ny % 2 == 0) ? 1 : -1;
        const int dx  = (ny % 2 == 0) ? -1 : 1;
        for (int ix = 0; ix < 8; ix++) {
            const int nx  = x0 + ix * dxs;
            const int nxn = nx + dx;
            const bool hasX = (nxn >= 0 && nxn < 8);
            const bool hasY = (ny > 0);
            const __hip_bfloat16* hxh = hasX ? (Hh + (size_t)nxn * Bsz * Hd) : nullptr;
            const __hip_bfloat16* hxl = hasX ? (Hl + (size_t)nxn * Bsz * Hd) : nullptr;
            const __hip_bfloat16* hyh = hasY ? (Hh + (size_t)nx  * Bsz * Hd) : nullptr;
            const __hip_bfloat16* hyl = hasY ? (Hl + (size_t)nx  * Bsz * Hd) : nullptr;
            const int kbeg = hasX ? 0   : 256;
            const int kend = hasY ? 512 : 256;

            gemm_mfma<<<dim3(12, MAXTILE, NPART), dim3(256), 0, stream>>>(
                hxh, hxl, hyh, hyl, Wht, Wlt, perm, tiletab, Gp, kcell, kbeg, kend);

            combine_logprob<<<dim3(Bsz), dim3(256), 0, stream>>>(
                Gp, samples, b1, b2, Wl1, bl1, Wl2, bl2,
                Hh + (size_t)nx * Bsz * Hd, Hl + (size_t)nx * Bsz * Hd,
                acc, out, nx * 8 + ny, kcell);
            kcell++;
        }
    }
}